// Round 2
// baseline (1043.102 us; speedup 1.0000x reference)
//
#include <hip/hip_runtime.h>

// SimpleRNN: B=16384, T=2048, I=1, H=20, O=1, fp32.
//
// Round-7. Round-6 post-mortem (854 us vs 619.6 baseline): ds_bpermute put
// ~120cy LDS latency + lgkmcnt waits inside the serial recurrence; 2 waves/
// SIMD couldn't hide it. Reverted to round-5 pure-DPP quad structure.
//
// Round-5 analysis: ~110 insts/step but 726 cyc/step measured => single
// wave/SIMD stalls ~3.3x over the wave64 issue floor (dependent-VALU
// latency + DPP hazards + trans latency, nothing to fill the gaps).
// Fix: TWO batches per thread (32768 threads, 512 waves, 1 wave/SIMD on
// half the SIMDs). The two recurrence chains are independent -- chain B
// fills chain A's stall cycles. Weights (100 W_hh values as 50 v2f pairs)
// are SHARED between the batches; only acc/rc/x state doubles (~175 VGPR).
//
// Also kept from round 6 (numerics validated, passed refcheck):
// tanh folded into weights: tanh(z) = 1 - 2*rcp(exp2(K*z)+1), K = 2*log2(e).
// Carry rc = rcp(exp2(K*z)+1) as state; W_hh pre-scaled by -2K, bias holds
// K*(b_ih+b_hh+rowsum(W_hh)), W_ih scaled by K. Activation is 3 insts/row
// (exp2, add, rcp); h = 1-2*rc reconstructed once in the epilogue.

#define RNN_T 2048
#define RNN_H 20
#define RNN_B 16384
#define NT4   (RNN_T / 4)

typedef float v2f __attribute__((ext_vector_type(2)));

template <int CTRL>
__device__ __forceinline__ float qb(float v) {
    // v_mov_b32_dpp quad_perm broadcast: CTRL = q * 0x55 broadcasts quad-lane q.
    return __builtin_bit_cast(
        float, __builtin_amdgcn_mov_dpp(__builtin_bit_cast(int, v), CTRL, 0xF, 0xF, true));
}

// Scaled weight pairs for row R (10 column-pairs, full 20 cols), plus folded
// bias. Raw row sum folds into bias with +K; weights get -2K (h = 1 - 2rc).
#define DECLW_ROW(R)                                                             \
    v2f wp##R##_0, wp##R##_1, wp##R##_2, wp##R##_3, wp##R##_4,                   \
        wp##R##_5, wp##R##_6, wp##R##_7, wp##R##_8, wp##R##_9;                   \
    v2f biasP##R, wihP##R;                                                       \
    {                                                                            \
        const float* wr = W_hh + (part * 5 + (R)) * RNN_H;                       \
        v2f a0 = *(const v2f*)(wr + 0);                                          \
        v2f a1 = *(const v2f*)(wr + 2);                                          \
        v2f a2 = *(const v2f*)(wr + 4);                                          \
        v2f a3 = *(const v2f*)(wr + 6);                                          \
        v2f a4 = *(const v2f*)(wr + 8);                                          \
        v2f a5 = *(const v2f*)(wr + 10);                                         \
        v2f a6 = *(const v2f*)(wr + 12);                                         \
        v2f a7 = *(const v2f*)(wr + 14);                                         \
        v2f a8 = *(const v2f*)(wr + 16);                                         \
        v2f a9 = *(const v2f*)(wr + 18);                                         \
        float rs = a0.x + a0.y + a1.x + a1.y + a2.x + a2.y + a3.x + a3.y +       \
                   a4.x + a4.y + a5.x + a5.y + a6.x + a6.y + a7.x + a7.y +       \
                   a8.x + a8.y + a9.x + a9.y;                                    \
        wp##R##_0 = a0 * WS;                                                     \
        wp##R##_1 = a1 * WS;                                                     \
        wp##R##_2 = a2 * WS;                                                     \
        wp##R##_3 = a3 * WS;                                                     \
        wp##R##_4 = a4 * WS;                                                     \
        wp##R##_5 = a5 * WS;                                                     \
        wp##R##_6 = a6 * WS;                                                     \
        wp##R##_7 = a7 * WS;                                                     \
        wp##R##_8 = a8 * WS;                                                     \
        wp##R##_9 = a9 * WS;                                                     \
        const int r = part * 5 + (R);                                            \
        biasP##R.x = KK * (b_ih[r] + b_hh[r] + rs);                              \
        biasP##R.y = 0.0f;                                                       \
        wihP##R.x  = KK * W_ih[r];                                               \
        wihP##R.y  = 0.0f;                                                       \
    }

// One column-pair block: build rc pair (2 DPP movs), fold into all 5 acc pairs
// with one v_pk_fma_f32 each. RA/RB are per-batch rc register names.
#define PBLK(I, CA, RA, CB, RB)                                                  \
    {                                                                            \
        v2f ha;                                                                  \
        ha.x = qb<CA>(RA);                                                       \
        ha.y = qb<CB>(RB);                                                       \
        acc0 = __builtin_elementwise_fma(wp0_##I, ha, acc0);                     \
        acc1 = __builtin_elementwise_fma(wp1_##I, ha, acc1);                     \
        acc2 = __builtin_elementwise_fma(wp2_##I, ha, acc2);                     \
        acc3 = __builtin_elementwise_fma(wp3_##I, ha, acc3);                     \
        acc4 = __builtin_elementwise_fma(wp4_##I, ha, acc4);                     \
    }

// One RNN step for batch-suffix S. Column c's source: quad-lane c/5,
// register rc{S}{c%5} -- wave-uniform quad_perm broadcasts only.
#define STEP(S, XS)                                                              \
    do {                                                                         \
        v2f xx;                                                                  \
        xx.x = (XS);                                                             \
        xx.y = (XS);                                                             \
        v2f acc0 = __builtin_elementwise_fma(wihP0, xx, biasP0);                 \
        v2f acc1 = __builtin_elementwise_fma(wihP1, xx, biasP1);                 \
        v2f acc2 = __builtin_elementwise_fma(wihP2, xx, biasP2);                 \
        v2f acc3 = __builtin_elementwise_fma(wihP3, xx, biasP3);                 \
        v2f acc4 = __builtin_elementwise_fma(wihP4, xx, biasP4);                 \
        PBLK(0, 0x00, rc##S##0, 0x00, rc##S##1)                                  \
        PBLK(1, 0x00, rc##S##2, 0x00, rc##S##3)                                  \
        PBLK(2, 0x00, rc##S##4, 0x55, rc##S##0)                                  \
        PBLK(3, 0x55, rc##S##1, 0x55, rc##S##2)                                  \
        PBLK(4, 0x55, rc##S##3, 0x55, rc##S##4)                                  \
        PBLK(5, 0xAA, rc##S##0, 0xAA, rc##S##1)                                  \
        PBLK(6, 0xAA, rc##S##2, 0xAA, rc##S##3)                                  \
        PBLK(7, 0xAA, rc##S##4, 0xFF, rc##S##0)                                  \
        PBLK(8, 0xFF, rc##S##1, 0xFF, rc##S##2)                                  \
        PBLK(9, 0xFF, rc##S##3, 0xFF, rc##S##4)                                  \
        rc##S##0 = __builtin_amdgcn_rcpf(                                        \
            __builtin_amdgcn_exp2f(acc0.x + acc0.y) + 1.0f);                     \
        rc##S##1 = __builtin_amdgcn_rcpf(                                        \
            __builtin_amdgcn_exp2f(acc1.x + acc1.y) + 1.0f);                     \
        rc##S##2 = __builtin_amdgcn_rcpf(                                        \
            __builtin_amdgcn_exp2f(acc2.x + acc2.y) + 1.0f);                     \
        rc##S##3 = __builtin_amdgcn_rcpf(                                        \
            __builtin_amdgcn_exp2f(acc3.x + acc3.y) + 1.0f);                     \
        rc##S##4 = __builtin_amdgcn_rcpf(                                        \
            __builtin_amdgcn_exp2f(acc4.x + acc4.y) + 1.0f);                     \
    } while (0)

__attribute__((amdgpu_flat_work_group_size(256, 256), amdgpu_waves_per_eu(1, 1)))
__global__ void rnn_fwd(const float* __restrict__ x,
                        const float* __restrict__ W_ih,
                        const float* __restrict__ W_hh,
                        const float* __restrict__ b_ih,
                        const float* __restrict__ b_hh,
                        const float* __restrict__ W_fc,
                        const float* __restrict__ b_fc,
                        float* __restrict__ out) {
    const int gid  = blockIdx.x * blockDim.x + threadIdx.x;
    const int qidx = gid >> 2;       // quad index: handles batches 2q, 2q+1
    const int part = gid & 3;        // quad-lane == which 5 rows this thread owns
    const int b0   = qidx * 2;
    const int b1   = b0 + 1;

    const float KK = 2.885390081777927f;   // 2*log2(e)
    const float WS = -2.0f * KK;           // W_hh scale

    DECLW_ROW(0) DECLW_ROW(1) DECLW_ROW(2) DECLW_ROW(3) DECLW_ROW(4)

    // rc = 0.5 <=> h = 0.
    float rcA0 = 0.5f, rcA1 = 0.5f, rcA2 = 0.5f, rcA3 = 0.5f, rcA4 = 0.5f;
    float rcB0 = 0.5f, rcB1 = 0.5f, rcB2 = 0.5f, rcB3 = 0.5f, rcB4 = 0.5f;

    const float4* xA4 = (const float4*)(x + (size_t)b0 * RNN_T);
    const float4* xB4 = (const float4*)(x + (size_t)b1 * RNN_T);

    float4 xvA = xA4[0];
    float4 xvB = xB4[0];
#pragma unroll 1
    for (int t4 = 0; t4 < NT4; ++t4) {
        const int tn = (t4 + 1 < NT4) ? (t4 + 1) : t4;
        const float4 xnA = xA4[tn];
        const float4 xnB = xB4[tn];
        STEP(A, xvA.x);
        STEP(B, xvB.x);
        STEP(A, xvA.y);
        STEP(B, xvB.y);
        STEP(A, xvA.z);
        STEP(B, xvB.z);
        STEP(A, xvA.w);
        STEP(B, xvB.w);
        xvA = xnA;
        xvB = xnB;
    }

    // h = 1 - 2*rc; out[b] = sigmoid(sum_o h[o]*wfc[o] + b_fc), quad-reduce.
    const int o0 = part * 5;
    const float wfc0 = W_fc[o0 + 0], wfc1 = W_fc[o0 + 1], wfc2 = W_fc[o0 + 2],
                wfc3 = W_fc[o0 + 3], wfc4 = W_fc[o0 + 4];

    float pA = fmaf(fmaf(-2.0f, rcA0, 1.0f), wfc0, 0.0f);
    pA = fmaf(fmaf(-2.0f, rcA1, 1.0f), wfc1, pA);
    pA = fmaf(fmaf(-2.0f, rcA2, 1.0f), wfc2, pA);
    pA = fmaf(fmaf(-2.0f, rcA3, 1.0f), wfc3, pA);
    pA = fmaf(fmaf(-2.0f, rcA4, 1.0f), wfc4, pA);
    float pB = fmaf(fmaf(-2.0f, rcB0, 1.0f), wfc0, 0.0f);
    pB = fmaf(fmaf(-2.0f, rcB1, 1.0f), wfc1, pB);
    pB = fmaf(fmaf(-2.0f, rcB2, 1.0f), wfc2, pB);
    pB = fmaf(fmaf(-2.0f, rcB3, 1.0f), wfc3, pB);
    pB = fmaf(fmaf(-2.0f, rcB4, 1.0f), wfc4, pB);

    pA += __shfl_xor(pA, 1, 64);
    pA += __shfl_xor(pA, 2, 64);
    pB += __shfl_xor(pB, 1, 64);
    pB += __shfl_xor(pB, 2, 64);

    if (part == 0) {
        const float zA = pA + b_fc[0];
        const float eA = __builtin_amdgcn_exp2f(-1.4426950408889634f * zA);
        out[b0] = __builtin_amdgcn_rcpf(1.0f + eA);
        const float zB = pB + b_fc[0];
        const float eB = __builtin_amdgcn_exp2f(-1.4426950408889634f * zB);
        out[b1] = __builtin_amdgcn_rcpf(1.0f + eB);
    }
}

extern "C" void kernel_launch(void* const* d_in, const int* in_sizes, int n_in,
                              void* d_out, int out_size, void* d_ws, size_t ws_size,
                              hipStream_t stream) {
    const float* x    = (const float*)d_in[0];
    const float* W_ih = (const float*)d_in[1];
    const float* W_hh = (const float*)d_in[2];
    const float* b_ih = (const float*)d_in[3];
    const float* b_hh = (const float*)d_in[4];
    const float* W_fc = (const float*)d_in[5];
    const float* b_fc = (const float*)d_in[6];
    float* out = (float*)d_out;

    const int threads = (RNN_B / 2) * 4;  // 32768 = 512 waves, 2 batches/thread
    const int block   = 256;
    rnn_fwd<<<threads / block, block, 0, stream>>>(x, W_ih, W_hh, b_ih, b_hh,
                                                   W_fc, b_fc, out);
}

// Round 3
// 807.409 us; speedup vs baseline: 1.2919x; 1.2919x over previous
//
#include <hip/hip_runtime.h>

// SimpleRNN: B=16384, T=2048, I=1, H=20, O=1, fp32.
//
// Round-8. Calibration from rounds 5/6/7:
//   r5: 4 thr/batch, 1 wave/SIMD, ~110 insts/step -> 726 cyc/step (3.3x stall)
//   r6: 8 thr/batch, 2 waves/SIMD, ds_bpermute exchange -> 947 cyc/step
//       (LDS latency in the serial recurrence ate the occupancy win)
//   r7: 2 batches/thread, 512 waves -> 563 cyc/step per wave but half the
//       chip idle; in-thread ILP did NOT reduce the ~3x stall factor.
// Conclusion: the stall holes are per-wave dead issue slots (DPP hazards,
// trans gaps, dependent-VALU latency); only a second hardware wave per SIMD
// fills them. So: 8 threads/batch (131072 thr = 2048 waves = 2/SIMD) with a
// DPP-ONLY cross-half exchange -- lane^6 partner built from two chained DPP
// movs (row_half_mirror 0x141 = lane^7, then quad_perm[1,0,3,2] 0xB1 =
// lane^3), pure VALU pipe, no LDS.
//
// Lane (q,hf) (oct = hf*4+q) computes row group rg = q ^ 2hf (rows rg*5..+4)
// over columns hf*10..hf*10+9. Exchange partner lane^6 = (q^2, 1-hf)
// computed the SAME rows' other column-half; after add, quad slot 0/1 of
// every hf-quad holds the rows that quad broadcasts next step (ctrls
// 0x00/0x55 only, registers rc0..rc4 = row rg*5+k).
//
// tanh folding kept (validated r6/r7): tanh(z) = 1 - 2*rcp(exp2(K*z)+1),
// K = 2*log2(e); W_hh pre-scaled by -2K, bias holds K*(b_ih+b_hh+rowsum),
// W_ih scaled by K; state rc = rcp(exp2(.)+1); h = 1-2rc in epilogue.
// Per-step per-thread: 5 init pk_fma + 5x(2 DPP + 5 pk_fma) + 5 hadd +
// (10 DPP + 5 add) exchange + 15 activation = ~75 insts.

#define RNN_T 2048
#define RNN_H 20
#define RNN_B 16384
#define NT4   (RNN_T / 4)

typedef float v2f __attribute__((ext_vector_type(2)));

template <int CTRL>
__device__ __forceinline__ float qb(float v) {
    // v_mov_b32_dpp: quad_perm (CTRL<=0xFF) or row mirror ctrls.
    return __builtin_bit_cast(
        float, __builtin_amdgcn_mov_dpp(__builtin_bit_cast(int, v), CTRL, 0xF, 0xF, true));
}

// lane^6 exchange: row_half_mirror (lane^7) then quad_perm [1,0,3,2] (lane^3).
__device__ __forceinline__ float xor6(float v) {
    return qb<0xB1>(qb<0x141>(v));
}

// Scaled weight pairs for local row R (5 column-pairs over this thread's 10
// cols) + folded bias. Row sum of raw W_hh over OWN cols folds in with +K;
// b_ih+b_hh and the x-projection belong to the hf==0 lane only.
#define DECLW_ROW(R)                                                             \
    v2f wp##R##_0, wp##R##_1, wp##R##_2, wp##R##_3, wp##R##_4;                   \
    v2f biasP##R, wihP##R;                                                       \
    {                                                                            \
        const float* wr = W_hh + (rg * 5 + (R)) * RNN_H + hf * 10;               \
        v2f a0 = *(const v2f*)(wr + 0);                                          \
        v2f a1 = *(const v2f*)(wr + 2);                                          \
        v2f a2 = *(const v2f*)(wr + 4);                                          \
        v2f a3 = *(const v2f*)(wr + 6);                                          \
        v2f a4 = *(const v2f*)(wr + 8);                                          \
        float rs = a0.x + a0.y + a1.x + a1.y + a2.x + a2.y + a3.x + a3.y +       \
                   a4.x + a4.y;                                                  \
        wp##R##_0 = a0 * WS;                                                     \
        wp##R##_1 = a1 * WS;                                                     \
        wp##R##_2 = a2 * WS;                                                     \
        wp##R##_3 = a3 * WS;                                                     \
        wp##R##_4 = a4 * WS;                                                     \
        const int r = rg * 5 + (R);                                              \
        biasP##R.x = KK * rs + ((hf == 0) ? KK * (b_ih[r] + b_hh[r]) : 0.0f);    \
        biasP##R.y = 0.0f;                                                       \
        wihP##R.x  = (hf == 0) ? KK * W_ih[r] : 0.0f;                            \
        wihP##R.y  = 0.0f;                                                       \
    }

// One column-pair block: build rc pair (2 DPP movs), fold into all 5 acc pairs
// with one v_pk_fma_f32 each.
#define PBLK(I, CA, RA, CB, RB)                                                  \
    {                                                                            \
        v2f ha;                                                                  \
        ha.x = qb<CA>(RA);                                                       \
        ha.y = qb<CB>(RB);                                                       \
        acc0 = __builtin_elementwise_fma(wp0_##I, ha, acc0);                     \
        acc1 = __builtin_elementwise_fma(wp1_##I, ha, acc1);                     \
        acc2 = __builtin_elementwise_fma(wp2_##I, ha, acc2);                     \
        acc3 = __builtin_elementwise_fma(wp3_##I, ha, acc3);                     \
        acc4 = __builtin_elementwise_fma(wp4_##I, ha, acc4);                     \
    }

// One RNN step. Local col j (0..9) sources quad slot j/5 (ctrl 0x00/0x55),
// register j%5 -- wave-uniform.
#define STEP(XS)                                                                 \
    do {                                                                         \
        v2f xx;                                                                  \
        xx.x = (XS);                                                             \
        xx.y = (XS);                                                             \
        v2f acc0 = __builtin_elementwise_fma(wihP0, xx, biasP0);                 \
        v2f acc1 = __builtin_elementwise_fma(wihP1, xx, biasP1);                 \
        v2f acc2 = __builtin_elementwise_fma(wihP2, xx, biasP2);                 \
        v2f acc3 = __builtin_elementwise_fma(wihP3, xx, biasP3);                 \
        v2f acc4 = __builtin_elementwise_fma(wihP4, xx, biasP4);                 \
        PBLK(0, 0x00, rc0, 0x00, rc1)                                            \
        PBLK(1, 0x00, rc2, 0x00, rc3)                                            \
        PBLK(2, 0x00, rc4, 0x55, rc0)                                            \
        PBLK(3, 0x55, rc1, 0x55, rc2)                                            \
        PBLK(4, 0x55, rc3, 0x55, rc4)                                            \
        float s0 = acc0.x + acc0.y;                                              \
        float s1 = acc1.x + acc1.y;                                              \
        float s2 = acc2.x + acc2.y;                                              \
        float s3 = acc3.x + acc3.y;                                              \
        float s4 = acc4.x + acc4.y;                                              \
        float f0 = s0 + xor6(s0);                                                \
        float f1 = s1 + xor6(s1);                                                \
        float f2 = s2 + xor6(s2);                                                \
        float f3 = s3 + xor6(s3);                                                \
        float f4 = s4 + xor6(s4);                                                \
        rc0 = __builtin_amdgcn_rcpf(__builtin_amdgcn_exp2f(f0) + 1.0f);          \
        rc1 = __builtin_amdgcn_rcpf(__builtin_amdgcn_exp2f(f1) + 1.0f);          \
        rc2 = __builtin_amdgcn_rcpf(__builtin_amdgcn_exp2f(f2) + 1.0f);          \
        rc3 = __builtin_amdgcn_rcpf(__builtin_amdgcn_exp2f(f3) + 1.0f);          \
        rc4 = __builtin_amdgcn_rcpf(__builtin_amdgcn_exp2f(f4) + 1.0f);          \
    } while (0)

__attribute__((amdgpu_flat_work_group_size(256, 256), amdgpu_waves_per_eu(2, 2)))
__global__ void rnn_fwd(const float* __restrict__ x,
                        const float* __restrict__ W_ih,
                        const float* __restrict__ W_hh,
                        const float* __restrict__ b_ih,
                        const float* __restrict__ b_hh,
                        const float* __restrict__ W_fc,
                        const float* __restrict__ b_fc,
                        float* __restrict__ out) {
    const int gid = blockIdx.x * blockDim.x + threadIdx.x;
    const int b   = gid >> 3;        // batch element (8 threads each)
    const int oct = gid & 7;         // octet lane
    const int q   = oct & 3;         // quad slot
    const int hf  = oct >> 2;        // column half: cols hf*10..hf*10+9
    const int rg  = q ^ (hf << 1);   // row group: rows rg*5..rg*5+4

    const float KK = 2.885390081777927f;   // 2*log2(e)
    const float WS = -2.0f * KK;           // W_hh scale

    DECLW_ROW(0) DECLW_ROW(1) DECLW_ROW(2) DECLW_ROW(3) DECLW_ROW(4)

    // rc = 0.5 <=> h = 0.
    float rc0 = 0.5f, rc1 = 0.5f, rc2 = 0.5f, rc3 = 0.5f, rc4 = 0.5f;

    const float4* x4 = (const float4*)(x + (size_t)b * RNN_T);

    float4 xv = x4[0];
#pragma unroll 1
    for (int t4 = 0; t4 < NT4; ++t4) {
        const int tn = (t4 + 1 < NT4) ? (t4 + 1) : t4;
        const float4 xn = x4[tn];
        STEP(xv.x);
        STEP(xv.y);
        STEP(xv.z);
        STEP(xv.w);
        xv = xn;
    }

    // h = 1 - 2*rc for rows rg*5..+4; dot with W_fc; quad-reduce (slots 0-3
    // of an hf-quad hold groups {rg} = {0,1,2,3} -> all 20 rows once).
    const int o0 = rg * 5;
    float p = fmaf(fmaf(-2.0f, rc0, 1.0f), W_fc[o0 + 0], 0.0f);
    p = fmaf(fmaf(-2.0f, rc1, 1.0f), W_fc[o0 + 1], p);
    p = fmaf(fmaf(-2.0f, rc2, 1.0f), W_fc[o0 + 2], p);
    p = fmaf(fmaf(-2.0f, rc3, 1.0f), W_fc[o0 + 3], p);
    p = fmaf(fmaf(-2.0f, rc4, 1.0f), W_fc[o0 + 4], p);
    p += __shfl_xor(p, 1, 64);
    p += __shfl_xor(p, 2, 64);
    if (oct == 0) {
        const float z = p + b_fc[0];
        const float e = __builtin_amdgcn_exp2f(-1.4426950408889634f * z);
        out[b] = __builtin_amdgcn_rcpf(1.0f + e);
    }
}

extern "C" void kernel_launch(void* const* d_in, const int* in_sizes, int n_in,
                              void* d_out, int out_size, void* d_ws, size_t ws_size,
                              hipStream_t stream) {
    const float* x    = (const float*)d_in[0];
    const float* W_ih = (const float*)d_in[1];
    const float* W_hh = (const float*)d_in[2];
    const float* b_ih = (const float*)d_in[3];
    const float* b_hh = (const float*)d_in[4];
    const float* W_fc = (const float*)d_in[5];
    const float* b_fc = (const float*)d_in[6];
    float* out = (float*)d_out;

    const int threads = RNN_B * 8;  // 131072 = 2048 waves = 2 waves/SIMD
    const int block   = 256;
    rnn_fwd<<<threads / block, block, 0, stream>>>(x, W_ih, W_hh, b_ih, b_hh,
                                                   W_fc, b_fc, out);
}

// Round 4
// 686.222 us; speedup vs baseline: 1.5201x; 1.1766x over previous
//
#include <hip/hip_runtime.h>

// SimpleRNN: B=16384, T=2048, I=1, H=20, O=1, fp32.
//
// Round-9: MFMA recurrence. r8 counters (VALUBusy 82% @ 2 waves/SIMD) proved
// the kernel is issued-VALU-bound (~44 issued cyc/batch-step vs ~12.5 FMA
// floor). The 400 FMAs/batch-step move to the matrix pipe:
//
//   C = (K*W_hh) @ h^T  via mfma_f32_16x16x32_bf16,
//     A-tiles = W (M=16 rows tile1, rows 16..19 tile2; K=32, cols 20..31 = 0)
//     B       = h^T (batches in N: n = lane&15)
//   C-layout (verified): col = lane&15 = batch, row = 4*(lane>>4)+reg.
//   B-frag:              n   = lane&15 = batch, k-block = lane>>4, j ~ reg.
//   => the activated C IS the next step's B fragment, in-lane. No DPP, no
//   LDS, no cross-lane ops anywhere in the recurrence.
//
//   K-slot map used for BOTH A and B: slot(g=lane>>4, j): j<4 -> c=4g+j,
//   j>=4 -> c=16+4g+(j-4) (c>=20 => 0-pad). Any consistent A/B k-placement
//   is a K-permutation of the dot product -> layout-order-proof.
//   Dword packing via v_perm_b32 (identical helper for A and B).
//
//   Precision: truncation split h = hi + lo (bf16 hi = top 16 bits), 4-term
//   product AhiBhi + AloBhi + AhiBlo + AloBlo => per-step err ~2^-16*||W||.
//   tanh folding kept (validated r6-r8): z pre-scaled by K=2*log2(e),
//   tanh = 1 - 2*rcp(exp2(z)+1), as C-init = K*(x*W_ih + b_ih + b_hh).
//
// 16 batches/wave -> 65536 threads = 1024 waves = 1 wave/SIMD, full chip.

#define RNN_T 2048
#define RNN_H 20
#define RNN_B 16384
#define NT4   (RNN_T / 4)

typedef float f32x4  __attribute__((ext_vector_type(4)));
typedef short bf16x8 __attribute__((ext_vector_type(8)));
typedef int   i32x4  __attribute__((ext_vector_type(4)));

// D = [bf16(b) : bf16(a)] by truncation; a lands in the LOW short (even elem).
__device__ __forceinline__ int pk_trunc(float a, float b) {
    return __builtin_amdgcn_perm(__builtin_bit_cast(int, b),
                                 __builtin_bit_cast(int, a), 0x07060302);
}
__device__ __forceinline__ float trunc_bf(float a) {
    return __builtin_bit_cast(float,
                              (int)(__builtin_bit_cast(int, a) & 0xffff0000));
}

__attribute__((amdgpu_flat_work_group_size(256, 256)))
__global__ void rnn_fwd(const float* __restrict__ x,
                        const float* __restrict__ W_ih,
                        const float* __restrict__ W_hh,
                        const float* __restrict__ b_ih,
                        const float* __restrict__ b_hh,
                        const float* __restrict__ W_fc,
                        const float* __restrict__ b_fc,
                        float* __restrict__ out) {
    const int gid  = blockIdx.x * blockDim.x + threadIdx.x;
    const int lane = threadIdx.x & 63;
    const int wid  = gid >> 6;        // global wave index
    const int B0   = wid * 16;        // this wave's batch block
    const int col  = lane & 15;       // batch slot / A-row m / B-col n
    const int g    = lane >> 4;       // k-block / C-row-block

    const float KS = 2.885390081777927f;  // 2*log2(e)

    // ---- Prologue: build A fragments (W_hh scaled by KS, split hi/lo) ----
    float w1[8], w2[8], l1[8], l2[8];
#pragma unroll
    for (int j = 0; j < 8; ++j) {
        const int c   = (j < 4) ? (4 * g + j) : (16 + 4 * g + (j - 4));
        const float m = (c < RNN_H) ? KS : 0.0f;
        const int cc  = (c < RNN_H) ? c : 0;
        w1[j] = m * W_hh[col * RNN_H + cc];                              // rows 0..15
        w2[j] = (col < 4) ? m * W_hh[(16 + col) * RNN_H + cc] : 0.0f;    // rows 16..19
        l1[j] = w1[j] - trunc_bf(w1[j]);
        l2[j] = w2[j] - trunc_bf(w2[j]);
    }
    i32x4 a1h, a1l, a2h, a2l;
    a1h.x = pk_trunc(w1[0], w1[1]); a1h.y = pk_trunc(w1[2], w1[3]);
    a1h.z = pk_trunc(w1[4], w1[5]); a1h.w = pk_trunc(w1[6], w1[7]);
    a1l.x = pk_trunc(l1[0], l1[1]); a1l.y = pk_trunc(l1[2], l1[3]);
    a1l.z = pk_trunc(l1[4], l1[5]); a1l.w = pk_trunc(l1[6], l1[7]);
    a2h.x = pk_trunc(w2[0], w2[1]); a2h.y = pk_trunc(w2[2], w2[3]);
    a2h.z = pk_trunc(w2[4], w2[5]); a2h.w = pk_trunc(w2[6], w2[7]);
    a2l.x = pk_trunc(l2[0], l2[1]); a2l.y = pk_trunc(l2[2], l2[3]);
    a2l.z = pk_trunc(l2[4], l2[5]); a2l.w = pk_trunc(l2[6], l2[7]);
    const bf16x8 A1h = __builtin_bit_cast(bf16x8, a1h);
    const bf16x8 A1l = __builtin_bit_cast(bf16x8, a1l);
    const bf16x8 A2h = __builtin_bit_cast(bf16x8, a2h);
    const bf16x8 A2l = __builtin_bit_cast(bf16x8, a2l);

    // Per-step C-init constants: rows r1 = 4g+reg (tile1), r2 = 16+4g+reg
    // (tile2, clamped; invalid rows masked at activation).
    f32x4 kwih1, kbias1, kwih2, kbias2;
#pragma unroll
    for (int reg = 0; reg < 4; ++reg) {
        const int r1 = 4 * g + reg;
        const int r2 = (16 + 4 * g + reg < RNN_H) ? (16 + 4 * g + reg) : (RNN_H - 1);
        kwih1[reg]  = KS * W_ih[r1];
        kbias1[reg] = KS * (b_ih[r1] + b_hh[r1]);
        kwih2[reg]  = KS * W_ih[r2];
        kbias2[reg] = KS * (b_ih[r2] + b_hh[r2]);
    }
    const float mk2 = (g == 0) ? 1.0f : 0.0f;   // tile2 rows valid iff g==0
    const float ms2 = -2.0f * mk2;

    // State: h as bf16 hi/lo B-fragments (h = 0 initially) + f32 copies.
    i32x4 zz; zz.x = 0; zz.y = 0; zz.z = 0; zz.w = 0;
    bf16x8 Bh = __builtin_bit_cast(bf16x8, zz);
    bf16x8 Bl = __builtin_bit_cast(bf16x8, zz);
    float h10 = 0.0f, h11 = 0.0f, h12 = 0.0f, h13 = 0.0f;
    float h20 = 0.0f, h21 = 0.0f, h22 = 0.0f, h23 = 0.0f;

    const float4* x4 = (const float4*)(x + (size_t)(B0 + col) * RNN_T);

#define STEP(XS)                                                                 \
    do {                                                                         \
        f32x4 xx = {(XS), (XS), (XS), (XS)};                                     \
        f32x4 acc1 = __builtin_elementwise_fma(kwih1, xx, kbias1);               \
        f32x4 acc2 = __builtin_elementwise_fma(kwih2, xx, kbias2);               \
        acc1 = __builtin_amdgcn_mfma_f32_16x16x32_bf16(A1h, Bh, acc1, 0, 0, 0);  \
        acc2 = __builtin_amdgcn_mfma_f32_16x16x32_bf16(A2h, Bh, acc2, 0, 0, 0);  \
        acc1 = __builtin_amdgcn_mfma_f32_16x16x32_bf16(A1l, Bh, acc1, 0, 0, 0);  \
        acc2 = __builtin_amdgcn_mfma_f32_16x16x32_bf16(A2l, Bh, acc2, 0, 0, 0);  \
        acc1 = __builtin_amdgcn_mfma_f32_16x16x32_bf16(A1h, Bl, acc1, 0, 0, 0);  \
        acc2 = __builtin_amdgcn_mfma_f32_16x16x32_bf16(A2h, Bl, acc2, 0, 0, 0);  \
        acc1 = __builtin_amdgcn_mfma_f32_16x16x32_bf16(A1l, Bl, acc1, 0, 0, 0);  \
        acc2 = __builtin_amdgcn_mfma_f32_16x16x32_bf16(A2l, Bl, acc2, 0, 0, 0);  \
        /* tanh: h = 1 - 2*rcp(exp2(z)+1); tile2 masked by mk2 */                \
        {                                                                        \
            float r;                                                             \
            r = __builtin_amdgcn_rcpf(__builtin_amdgcn_exp2f(acc1.x) + 1.0f);    \
            h10 = fmaf(-2.0f, r, 1.0f);                                          \
            r = __builtin_amdgcn_rcpf(__builtin_amdgcn_exp2f(acc1.y) + 1.0f);    \
            h11 = fmaf(-2.0f, r, 1.0f);                                          \
            r = __builtin_amdgcn_rcpf(__builtin_amdgcn_exp2f(acc1.z) + 1.0f);    \
            h12 = fmaf(-2.0f, r, 1.0f);                                          \
            r = __builtin_amdgcn_rcpf(__builtin_amdgcn_exp2f(acc1.w) + 1.0f);    \
            h13 = fmaf(-2.0f, r, 1.0f);                                          \
            r = __builtin_amdgcn_rcpf(__builtin_amdgcn_exp2f(acc2.x) + 1.0f);    \
            h20 = fmaf(ms2, r, mk2);                                             \
            r = __builtin_amdgcn_rcpf(__builtin_amdgcn_exp2f(acc2.y) + 1.0f);    \
            h21 = fmaf(ms2, r, mk2);                                             \
            r = __builtin_amdgcn_rcpf(__builtin_amdgcn_exp2f(acc2.z) + 1.0f);    \
            h22 = fmaf(ms2, r, mk2);                                             \
            r = __builtin_amdgcn_rcpf(__builtin_amdgcn_exp2f(acc2.w) + 1.0f);    \
            h23 = fmaf(ms2, r, mk2);                                             \
        }                                                                        \
        /* rebuild B-fragments: hi = trunc16, lo = remainder (trunc16'd) */      \
        {                                                                        \
            i32x4 bh, bl;                                                        \
            bh.x = pk_trunc(h10, h11);                                           \
            bh.y = pk_trunc(h12, h13);                                           \
            bh.z = pk_trunc(h20, h21);                                           \
            bh.w = pk_trunc(h22, h23);                                           \
            bl.x = pk_trunc(h10 - trunc_bf(h10), h11 - trunc_bf(h11));           \
            bl.y = pk_trunc(h12 - trunc_bf(h12), h13 - trunc_bf(h13));           \
            bl.z = pk_trunc(h20 - trunc_bf(h20), h21 - trunc_bf(h21));           \
            bl.w = pk_trunc(h22 - trunc_bf(h22), h23 - trunc_bf(h23));           \
            Bh = __builtin_bit_cast(bf16x8, bh);                                 \
            Bl = __builtin_bit_cast(bf16x8, bl);                                 \
        }                                                                        \
    } while (0)

    float4 xv = x4[0];
#pragma unroll 1
    for (int t4 = 0; t4 < NT4; ++t4) {
        const int tn = (t4 + 1 < NT4) ? (t4 + 1) : t4;
        const float4 xn = x4[tn];
        STEP(xv.x);
        STEP(xv.y);
        STEP(xv.z);
        STEP(xv.w);
        xv = xn;
    }
#undef STEP

    // Epilogue: lane holds h[b=B0+col][rows 4g..4g+3] and (g==0) rows 16..19.
    // p = sum over own rows; reduce the 4 g-groups (lanes l, l^16, l^32, l^48).
    float p = h10 * W_fc[4 * g + 0];
    p = fmaf(h11, W_fc[4 * g + 1], p);
    p = fmaf(h12, W_fc[4 * g + 2], p);
    p = fmaf(h13, W_fc[4 * g + 3], p);
    p = fmaf(h20, W_fc[16], p);   // h2* are 0 for g!=0
    p = fmaf(h21, W_fc[17], p);
    p = fmaf(h22, W_fc[18], p);
    p = fmaf(h23, W_fc[19], p);
    p += __shfl_xor(p, 16, 64);
    p += __shfl_xor(p, 32, 64);
    if (lane < 16) {
        const float z = p + b_fc[0];
        const float e = __builtin_amdgcn_exp2f(-1.4426950408889634f * z);
        out[B0 + lane] = __builtin_amdgcn_rcpf(1.0f + e);
    }
}

extern "C" void kernel_launch(void* const* d_in, const int* in_sizes, int n_in,
                              void* d_out, int out_size, void* d_ws, size_t ws_size,
                              hipStream_t stream) {
    const float* x    = (const float*)d_in[0];
    const float* W_ih = (const float*)d_in[1];
    const float* W_hh = (const float*)d_in[2];
    const float* b_ih = (const float*)d_in[3];
    const float* b_hh = (const float*)d_in[4];
    const float* W_fc = (const float*)d_in[5];
    const float* b_fc = (const float*)d_in[6];
    float* out = (float*)d_out;

    const int threads = (RNN_B / 16) * 64;  // 65536 = 1024 waves = 1/SIMD
    const int block   = 256;
    rnn_fwd<<<threads / block, block, 0, stream>>>(x, W_ih, W_hh, b_ih, b_hh,
                                                   W_fc, b_fc, out);
}

// Round 5
// 674.237 us; speedup vs baseline: 1.5471x; 1.0178x over previous
//
#include <hip/hip_runtime.h>

// SimpleRNN: B=16384, T=2048, I=1, H=20, O=1, fp32.
//
// Round-10. r9 (MFMA recurrence, 590 us counter-time) post-mortem:
//   691 cyc/step = ~435 VALU-issue + ~136 matrix + ~120 stall.
//   Static count says 56 non-trans VALU = 112 cyc => the 16 trans ops
//   (8 exp2 + 8 rcp @ ~20 cyc wave64) are ~320 cyc -- the dominant cost.
// Changes vs r9 (layout/slot-map/pack byte-identical, refcheck-passing):
//   (a) quad-batched reciprocal: r = rcp(a0*a1*a2*a3), back-substitute
//       partial products -> all four 1/(e+1) from ONE rcp. 8 rcp -> 2 rcp
//       (+10 muls). Overflow-safe: e <= 2^11 @ |x|<=5.5 -> prod <= 2^44.
//   (b) drop the 2 AloBlo MFMAs (lo x lo term ~2^-16 relative, far below
//       the fast-tanh error that dominates absmax). 8 -> 6 MFMAs, chains
//       4 -> 3 deep, interleaved across the two tiles.
//
//   C = (K*W_hh) @ h^T  via mfma_f32_16x16x32_bf16,
//   C-layout: col = lane&15 = batch, row = 4*(lane>>4)+reg; this IS the
//   next step's B fragment in-lane. No DPP/LDS/cross-lane in the loop.
//   tanh folding: z pre-scaled by K=2*log2(e); tanh = 1 - 2*rcp(exp2(z)+1).
//
// 16 batches/wave -> 65536 threads = 1024 waves = 1 wave/SIMD, full chip.

#define RNN_T 2048
#define RNN_H 20
#define RNN_B 16384
#define NT4   (RNN_T / 4)

typedef float f32x4  __attribute__((ext_vector_type(4)));
typedef short bf16x8 __attribute__((ext_vector_type(8)));
typedef int   i32x4  __attribute__((ext_vector_type(4)));

// D = [bf16(b) : bf16(a)] by truncation; a lands in the LOW short (even elem).
__device__ __forceinline__ int pk_trunc(float a, float b) {
    return __builtin_amdgcn_perm(__builtin_bit_cast(int, b),
                                 __builtin_bit_cast(int, a), 0x07060302);
}
__device__ __forceinline__ float trunc_bf(float a) {
    return __builtin_bit_cast(float,
                              (int)(__builtin_bit_cast(int, a) & 0xffff0000));
}

__attribute__((amdgpu_flat_work_group_size(256, 256)))
__global__ void rnn_fwd(const float* __restrict__ x,
                        const float* __restrict__ W_ih,
                        const float* __restrict__ W_hh,
                        const float* __restrict__ b_ih,
                        const float* __restrict__ b_hh,
                        const float* __restrict__ W_fc,
                        const float* __restrict__ b_fc,
                        float* __restrict__ out) {
    const int gid  = blockIdx.x * blockDim.x + threadIdx.x;
    const int lane = threadIdx.x & 63;
    const int wid  = gid >> 6;        // global wave index
    const int B0   = wid * 16;        // this wave's batch block
    const int col  = lane & 15;       // batch slot / A-row m / B-col n
    const int g    = lane >> 4;       // k-block / C-row-block

    const float KS = 2.885390081777927f;  // 2*log2(e)

    // ---- Prologue: build A fragments (W_hh scaled by KS, split hi/lo) ----
    float w1[8], w2[8], l1[8], l2[8];
#pragma unroll
    for (int j = 0; j < 8; ++j) {
        const int c   = (j < 4) ? (4 * g + j) : (16 + 4 * g + (j - 4));
        const float m = (c < RNN_H) ? KS : 0.0f;
        const int cc  = (c < RNN_H) ? c : 0;
        w1[j] = m * W_hh[col * RNN_H + cc];                              // rows 0..15
        w2[j] = (col < 4) ? m * W_hh[(16 + col) * RNN_H + cc] : 0.0f;    // rows 16..19
        l1[j] = w1[j] - trunc_bf(w1[j]);
        l2[j] = w2[j] - trunc_bf(w2[j]);
    }
    i32x4 a1h, a1l, a2h, a2l;
    a1h.x = pk_trunc(w1[0], w1[1]); a1h.y = pk_trunc(w1[2], w1[3]);
    a1h.z = pk_trunc(w1[4], w1[5]); a1h.w = pk_trunc(w1[6], w1[7]);
    a1l.x = pk_trunc(l1[0], l1[1]); a1l.y = pk_trunc(l1[2], l1[3]);
    a1l.z = pk_trunc(l1[4], l1[5]); a1l.w = pk_trunc(l1[6], l1[7]);
    a2h.x = pk_trunc(w2[0], w2[1]); a2h.y = pk_trunc(w2[2], w2[3]);
    a2h.z = pk_trunc(w2[4], w2[5]); a2h.w = pk_trunc(w2[6], w2[7]);
    a2l.x = pk_trunc(l2[0], l2[1]); a2l.y = pk_trunc(l2[2], l2[3]);
    a2l.z = pk_trunc(l2[4], l2[5]); a2l.w = pk_trunc(l2[6], l2[7]);
    const bf16x8 A1h = __builtin_bit_cast(bf16x8, a1h);
    const bf16x8 A1l = __builtin_bit_cast(bf16x8, a1l);
    const bf16x8 A2h = __builtin_bit_cast(bf16x8, a2h);
    const bf16x8 A2l = __builtin_bit_cast(bf16x8, a2l);

    // Per-step C-init constants: rows r1 = 4g+reg (tile1), r2 = 16+4g+reg
    // (tile2, clamped; invalid rows masked at activation).
    f32x4 kwih1, kbias1, kwih2, kbias2;
#pragma unroll
    for (int reg = 0; reg < 4; ++reg) {
        const int r1 = 4 * g + reg;
        const int r2 = (16 + 4 * g + reg < RNN_H) ? (16 + 4 * g + reg) : (RNN_H - 1);
        kwih1[reg]  = KS * W_ih[r1];
        kbias1[reg] = KS * (b_ih[r1] + b_hh[r1]);
        kwih2[reg]  = KS * W_ih[r2];
        kbias2[reg] = KS * (b_ih[r2] + b_hh[r2]);
    }
    const float mk2 = (g == 0) ? 1.0f : 0.0f;   // tile2 rows valid iff g==0
    const float ms2 = -2.0f * mk2;

    // State: h as bf16 hi/lo B-fragments (h = 0 initially) + f32 copies.
    i32x4 zz; zz.x = 0; zz.y = 0; zz.z = 0; zz.w = 0;
    bf16x8 Bh = __builtin_bit_cast(bf16x8, zz);
    bf16x8 Bl = __builtin_bit_cast(bf16x8, zz);
    float h10 = 0.0f, h11 = 0.0f, h12 = 0.0f, h13 = 0.0f;
    float h20 = 0.0f, h21 = 0.0f, h22 = 0.0f, h23 = 0.0f;

    const float4* x4 = (const float4*)(x + (size_t)(B0 + col) * RNN_T);

#define STEP(XS)                                                                 \
    do {                                                                         \
        f32x4 xx = {(XS), (XS), (XS), (XS)};                                     \
        f32x4 acc1 = __builtin_elementwise_fma(kwih1, xx, kbias1);               \
        f32x4 acc2 = __builtin_elementwise_fma(kwih2, xx, kbias2);               \
        acc1 = __builtin_amdgcn_mfma_f32_16x16x32_bf16(A1h, Bh, acc1, 0, 0, 0);  \
        acc2 = __builtin_amdgcn_mfma_f32_16x16x32_bf16(A2h, Bh, acc2, 0, 0, 0);  \
        acc1 = __builtin_amdgcn_mfma_f32_16x16x32_bf16(A1l, Bh, acc1, 0, 0, 0);  \
        acc2 = __builtin_amdgcn_mfma_f32_16x16x32_bf16(A2l, Bh, acc2, 0, 0, 0);  \
        acc1 = __builtin_amdgcn_mfma_f32_16x16x32_bf16(A1h, Bl, acc1, 0, 0, 0);  \
        acc2 = __builtin_amdgcn_mfma_f32_16x16x32_bf16(A2h, Bl, acc2, 0, 0, 0);  \
        /* tanh: h = 1 - 2*rcp(exp2(z)+1); ONE rcp per quad via product    */    \
        /* trick; tile2 masked by mk2/ms2.                                 */    \
        {                                                                        \
            const float e0 = __builtin_amdgcn_exp2f(acc1.x);                     \
            const float e1 = __builtin_amdgcn_exp2f(acc1.y);                     \
            const float e2 = __builtin_amdgcn_exp2f(acc1.z);                     \
            const float e3 = __builtin_amdgcn_exp2f(acc1.w);                     \
            const float a0 = e0 + 1.0f, a1 = e1 + 1.0f;                          \
            const float a2 = e2 + 1.0f, a3 = e3 + 1.0f;                          \
            const float p01 = a0 * a1, p23 = a2 * a3;                            \
            const float rq  = __builtin_amdgcn_rcpf(p01 * p23);                  \
            const float r01 = rq * p23, r23 = rq * p01;                          \
            h10 = fmaf(-2.0f, r01 * a1, 1.0f);                                   \
            h11 = fmaf(-2.0f, r01 * a0, 1.0f);                                   \
            h12 = fmaf(-2.0f, r23 * a3, 1.0f);                                   \
            h13 = fmaf(-2.0f, r23 * a2, 1.0f);                                   \
            const float f0 = __builtin_amdgcn_exp2f(acc2.x);                     \
            const float f1 = __builtin_amdgcn_exp2f(acc2.y);                     \
            const float f2 = __builtin_amdgcn_exp2f(acc2.z);                     \
            const float f3 = __builtin_amdgcn_exp2f(acc2.w);                     \
            const float b0 = f0 + 1.0f, b1 = f1 + 1.0f;                          \
            const float b2 = f2 + 1.0f, b3 = f3 + 1.0f;                          \
            const float q01 = b0 * b1, q23 = b2 * b3;                            \
            const float sq  = __builtin_amdgcn_rcpf(q01 * q23);                  \
            const float s01 = sq * q23, s23 = sq * q01;                          \
            h20 = fmaf(ms2, s01 * b1, mk2);                                      \
            h21 = fmaf(ms2, s01 * b0, mk2);                                      \
            h22 = fmaf(ms2, s23 * b3, mk2);                                      \
            h23 = fmaf(ms2, s23 * b2, mk2);                                      \
        }                                                                        \
        /* rebuild B-fragments: hi = trunc16, lo = remainder (trunc16'd) */      \
        {                                                                        \
            i32x4 bh, bl;                                                        \
            bh.x = pk_trunc(h10, h11);                                           \
            bh.y = pk_trunc(h12, h13);                                           \
            bh.z = pk_trunc(h20, h21);                                           \
            bh.w = pk_trunc(h22, h23);                                           \
            bl.x = pk_trunc(h10 - trunc_bf(h10), h11 - trunc_bf(h11));           \
            bl.y = pk_trunc(h12 - trunc_bf(h12), h13 - trunc_bf(h13));           \
            bl.z = pk_trunc(h20 - trunc_bf(h20), h21 - trunc_bf(h21));           \
            bl.w = pk_trunc(h22 - trunc_bf(h22), h23 - trunc_bf(h23));           \
            Bh = __builtin_bit_cast(bf16x8, bh);                                 \
            Bl = __builtin_bit_cast(bf16x8, bl);                                 \
        }                                                                        \
    } while (0)

    float4 xv = x4[0];
#pragma unroll 1
    for (int t4 = 0; t4 < NT4; ++t4) {
        const int tn = (t4 + 1 < NT4) ? (t4 + 1) : t4;
        const float4 xn = x4[tn];
        STEP(xv.x);
        STEP(xv.y);
        STEP(xv.z);
        STEP(xv.w);
        xv = xn;
    }
#undef STEP

    // Epilogue: lane holds h[b=B0+col][rows 4g..4g+3] and (g==0) rows 16..19.
    // p = sum over own rows; reduce the 4 g-groups (lanes l, l^16, l^32, l^48).
    float p = h10 * W_fc[4 * g + 0];
    p = fmaf(h11, W_fc[4 * g + 1], p);
    p = fmaf(h12, W_fc[4 * g + 2], p);
    p = fmaf(h13, W_fc[4 * g + 3], p);
    p = fmaf(h20, W_fc[16], p);   // h2* are 0 for g!=0
    p = fmaf(h21, W_fc[17], p);
    p = fmaf(h22, W_fc[18], p);
    p = fmaf(h23, W_fc[19], p);
    p += __shfl_xor(p, 16, 64);
    p += __shfl_xor(p, 32, 64);
    if (lane < 16) {
        const float z = p + b_fc[0];
        const float e = __builtin_amdgcn_exp2f(-1.4426950408889634f * z);
        out[B0 + lane] = __builtin_amdgcn_rcpf(1.0f + e);
    }
}

extern "C" void kernel_launch(void* const* d_in, const int* in_sizes, int n_in,
                              void* d_out, int out_size, void* d_ws, size_t ws_size,
                              hipStream_t stream) {
    const float* x    = (const float*)d_in[0];
    const float* W_ih = (const float*)d_in[1];
    const float* W_hh = (const float*)d_in[2];
    const float* b_ih = (const float*)d_in[3];
    const float* b_hh = (const float*)d_in[4];
    const float* W_fc = (const float*)d_in[5];
    const float* b_fc = (const float*)d_in[6];
    float* out = (float*)d_out;

    const int threads = (RNN_B / 16) * 64;  // 65536 = 1024 waves = 1/SIMD
    const int block   = 256;
    rnn_fwd<<<threads / block, block, 0, stream>>>(x, W_ih, W_hh, b_ih, b_hh,
                                                   W_fc, b_fc, out);
}